// Round 11
// baseline (1208.363 us; speedup 1.0000x reference)
//
#include <hip/hip_runtime.h>
#include <hip/hip_fp16.h>

// GCN: N=100000 nodes, E=1600000 edges, dims 128 -> 64 -> 32.
// NO CSR: edges bucketed once (packed r<<7|c&127), then each layer aggregates
// directly per bucket into an LDS fp32 accumulator (ds_add_f32), gathering
// fp16 source rows. Eliminates bktscan/pass2/adj/ptr entirely.
//   pass1: partition packed edges into 782 buckets of 128 dest nodes.
//   deg:   per-bucket histogram -> dinv = rsqrt(deg+1).
//   gemm1: g1 = fp16(dinv*(x@W1)); 64-node x-tile in LDS.
//   agg1:  per bucket: LDS acc[128][64] += g1[r]; h1=relu(di*(acc+self)+b1);
//          g2 = fp16(di*(h1@W2)).
//   agg2:  per bucket: LDS acc[128][32] += g2[r]; out = di*(acc+self)+b2.

#define NNODES 100000
#define NEDGES 1600000
#define IN_DIM 128
#define HID 64
#define OUTD 32

#define BKT_NODES 128
#define NBUK 782                        // ceil(100000/128)
#define BKT_CAP 3584                    // slots/bucket; mean load 2048
#define P1_BLOCKS 256
#define P1_CHUNK (NEDGES / P1_BLOCKS)   // 6250 exactly

// ---- bucket build ----

__global__ __launch_bounds__(256) void k_pass1(const int* __restrict__ row,
                                               const int* __restrict__ col,
                                               int* __restrict__ gcur,
                                               unsigned int* __restrict__ pairbuf) {
    __shared__ int lcnt[NBUK];
    __shared__ int lbase[NBUK];
    int t = threadIdx.x;
    int e0 = blockIdx.x * P1_CHUNK;
    int e1 = e0 + P1_CHUNK;
    for (int j = t; j < NBUK; j += 256) lcnt[j] = 0;
    __syncthreads();
    for (int e = e0 + t; e < e1; e += 256)
        atomicAdd(&lcnt[col[e] >> 7], 1);
    __syncthreads();
    for (int j = t; j < NBUK; j += 256) {
        int n = lcnt[j];
        lbase[j] = (n > 0) ? atomicAdd(&gcur[j], n) : 0;
    }
    __syncthreads();
    for (int j = t; j < NBUK; j += 256) lcnt[j] = 0;
    __syncthreads();
    for (int e = e0 + t; e < e1; e += 256) {
        int c = col[e];
        unsigned int pk = ((unsigned int)row[e] << 7) | (unsigned int)(c & 127);
        int b = c >> 7;
        int pos = lbase[b] + atomicAdd(&lcnt[b], 1);
        if (pos < BKT_CAP) pairbuf[(size_t)b * BKT_CAP + pos] = pk;
    }
}

// per-bucket degree histogram -> dinv
__global__ __launch_bounds__(256) void k_deg(const unsigned int* __restrict__ pairbuf,
                                             const int* __restrict__ gcur,
                                             float* __restrict__ dinv) {
    __shared__ int cnt[BKT_NODES];
    int b = blockIdx.x, t = threadIdx.x;
    int c0 = b * BKT_NODES;
    int size = gcur[b]; if (size > BKT_CAP) size = BKT_CAP;
    if (t < BKT_NODES) cnt[t] = 0;
    __syncthreads();
    const unsigned int* pp = pairbuf + (size_t)b * BKT_CAP;
    for (int k = t; k < size; k += 256) atomicAdd(&cnt[pp[k] & 127u], 1);
    __syncthreads();
    int nb = NNODES - c0; if (nb > BKT_NODES) nb = BKT_NODES;
    if (t < nb) dinv[c0 + t] = rsqrtf((float)cnt[t] + 1.0f);  // +1 self-loop
}

// ---- layer kernels ----

// g1 = fp16(dinv * (x @ W1)); 64-node x-tile staged in LDS via coalesced float4.
#define TILE 64
#define NT 16
__global__ __launch_bounds__(256) void k_gemm1(const float* __restrict__ x,
                                               const float* __restrict__ W1,
                                               const float* __restrict__ dinv,
                                               __half* __restrict__ g1) {
    __shared__ float shx[TILE][IN_DIM];  // 32 KB
    int t = threadIdx.x;
    int nbase = blockIdx.x * TILE;

    const float4* xg = reinterpret_cast<const float4*>(x + (size_t)nbase * IN_DIM);
    float4* shx4 = reinterpret_cast<float4*>(&shx[0][0]);
    int lim = (NNODES - nbase) * (IN_DIM / 4);
    if (lim > TILE * (IN_DIM / 4)) lim = TILE * (IN_DIM / 4);
#pragma unroll
    for (int it = 0; it < 8; ++it) {
        int idx = t + it * 256;
        if (idx < lim) shx4[idx] = xg[idx];
    }
    __syncthreads();

    int w = t >> 6;
    int lane = t & 63;
    int n0 = w * NT;

    float acc[NT];
#pragma unroll
    for (int n = 0; n < NT; ++n) acc[n] = 0.0f;

    for (int kc = 0; kc < IN_DIM / 4; ++kc) {
        float w0 = W1[(kc * 4 + 0) * HID + lane];  // coalesced 256B, L1-hot
        float w1 = W1[(kc * 4 + 1) * HID + lane];
        float w2 = W1[(kc * 4 + 2) * HID + lane];
        float w3 = W1[(kc * 4 + 3) * HID + lane];
#pragma unroll
        for (int n = 0; n < NT; ++n) {
            float4 xv = *reinterpret_cast<const float4*>(&shx[n0 + n][kc * 4]);
            acc[n] = fmaf(xv.x, w0, acc[n]);
            acc[n] = fmaf(xv.y, w1, acc[n]);
            acc[n] = fmaf(xv.z, w2, acc[n]);
            acc[n] = fmaf(xv.w, w3, acc[n]);
        }
    }
#pragma unroll
    for (int n = 0; n < NT; ++n) {
        int node = nbase + n0 + n;
        if (node < NNODES)
            g1[(unsigned)node * HID + lane] = __float2half(dinv[node] * acc[n]);
    }
}

// layer1 agg + layer2 gemm, bucket-direct. One block per bucket.
// Edge loop: lanes 0-31 = edge A's 32 half2 feats, lanes 32-63 = edge B's.
// Gather -> LDS ds_add_f32 (no loop-carried dep => deep pipelining).
__global__ __launch_bounds__(256) void k_agg1(const __half2* __restrict__ g1,
                                              const unsigned int* __restrict__ pairbuf,
                                              const int* __restrict__ gcur,
                                              const float* __restrict__ dinv,
                                              const float* __restrict__ b1,
                                              const float* __restrict__ W2,
                                              __half* __restrict__ g2) {
    __shared__ float sacc[BKT_NODES][HID];  // 32 KB
    int b = blockIdx.x, t = threadIdx.x;
    int c0 = b * BKT_NODES;
    int size = gcur[b]; if (size > BKT_CAP) size = BKT_CAP;
    int nb = NNODES - c0; if (nb > BKT_NODES) nb = BKT_NODES;

    {   // zero accumulator (float4)
        float4* s4 = reinterpret_cast<float4*>(&sacc[0][0]);
        float4 z = make_float4(0.f, 0.f, 0.f, 0.f);
        for (int k = t; k < BKT_NODES * HID / 4; k += 256) s4[k] = z;
    }
    __syncthreads();

    unsigned lane = t & 63;
    int w = t >> 6;
    unsigned hi = lane >> 5;   // which edge of the pair
    unsigned hl = lane & 31;   // half2 index in row

    const unsigned int* pp = pairbuf + (size_t)b * BKT_CAP;
    int s0 = (size * w) >> 2;
    int s1 = (size * (w + 1)) >> 2;
    int k = s0;
    for (; k + 8 <= s1; k += 8) {   // 8 edges: 4 pk loads + 4 gathers + 8 ds_add
        unsigned pk0 = pp[k + 0 + hi];
        unsigned pk1 = pp[k + 2 + hi];
        unsigned pk2 = pp[k + 4 + hi];
        unsigned pk3 = pp[k + 6 + hi];
        float2 f0 = __half22float2(g1[((pk0 >> 7) << 5) + hl]);
        float2 f1 = __half22float2(g1[((pk1 >> 7) << 5) + hl]);
        float2 f2 = __half22float2(g1[((pk2 >> 7) << 5) + hl]);
        float2 f3 = __half22float2(g1[((pk3 >> 7) << 5) + hl]);
        unsigned cA = pk0 & 127u, cB = pk1 & 127u, cC = pk2 & 127u, cD = pk3 & 127u;
        atomicAdd(&sacc[cA][2 * hl], f0.x); atomicAdd(&sacc[cA][2 * hl + 1], f0.y);
        atomicAdd(&sacc[cB][2 * hl], f1.x); atomicAdd(&sacc[cB][2 * hl + 1], f1.y);
        atomicAdd(&sacc[cC][2 * hl], f2.x); atomicAdd(&sacc[cC][2 * hl + 1], f2.y);
        atomicAdd(&sacc[cD][2 * hl], f3.x); atomicAdd(&sacc[cD][2 * hl + 1], f3.y);
    }
    for (; k + 2 <= s1; k += 2) {
        unsigned pk = pp[k + hi];
        float2 f = __half22float2(g1[((pk >> 7) << 5) + hl]);
        unsigned c = pk & 127u;
        atomicAdd(&sacc[c][2 * hl], f.x); atomicAdd(&sacc[c][2 * hl + 1], f.y);
    }
    if (k < s1 && hi == 0) {   // odd tail edge
        unsigned pk = pp[k];
        float2 f = __half22float2(g1[((pk >> 7) << 5) + hl]);
        unsigned c = pk & 127u;
        atomicAdd(&sacc[c][2 * hl], f.x); atomicAdd(&sacc[c][2 * hl + 1], f.y);
    }
    __syncthreads();

    // finalize h1 = relu(di*(acc+self)+b1) in place
    for (int idx = t; idx < nb * 32; idx += 256) {
        int d = idx >> 5; int h = idx & 31;
        float2 self = __half22float2(g1[((unsigned)(c0 + d) << 5) + h]);
        float di = dinv[c0 + d];
        float2 bb = *reinterpret_cast<const float2*>(&b1[2 * h]);
        float2 a = *reinterpret_cast<float2*>(&sacc[d][2 * h]);
        a.x = fmaxf(fmaf(di, a.x + self.x, bb.x), 0.f);
        a.y = fmaxf(fmaf(di, a.y + self.y, bb.y), 0.f);
        *reinterpret_cast<float2*>(&sacc[d][2 * h]) = a;
    }
    __syncthreads();

    // matvec h1(64) @ W2(64x32) per node; wave w handles 32 nodes
    unsigned j2 = lane & 31;
    unsigned half = lane >> 5;
    int dend = (w + 1) * 32; if (dend > nb) dend = nb;
    for (int d = w * 32; d < dend; ++d) {
        float mv = 0.f;
#pragma unroll
        for (int j = 0; j < 32; ++j) {
            unsigned jj = half * 32 + j;
            mv = fmaf(sacc[d][jj], W2[jj * OUTD + j2], mv);  // sacc broadcast, W2 L1-hot
        }
        mv += __shfl_xor(mv, 32);
        if (half == 0) {
            float di = dinv[c0 + d];
            g2[((unsigned)(c0 + d) << 5) + j2] = __float2half(di * mv);
        }
    }
}

// layer2 agg, bucket-direct: lane quarter q = edge select, 4 edges/gather-pair.
__global__ __launch_bounds__(256) void k_agg2(const __half2* __restrict__ g2,
                                              const unsigned int* __restrict__ pairbuf,
                                              const int* __restrict__ gcur,
                                              const float* __restrict__ dinv,
                                              const float* __restrict__ b2,
                                              float2* __restrict__ out) {
    __shared__ float sacc[BKT_NODES][OUTD];  // 16 KB
    int b = blockIdx.x, t = threadIdx.x;
    int c0 = b * BKT_NODES;
    int size = gcur[b]; if (size > BKT_CAP) size = BKT_CAP;
    int nb = NNODES - c0; if (nb > BKT_NODES) nb = BKT_NODES;

    {
        float4* s4 = reinterpret_cast<float4*>(&sacc[0][0]);
        float4 z = make_float4(0.f, 0.f, 0.f, 0.f);
        for (int k = t; k < BKT_NODES * OUTD / 4; k += 256) s4[k] = z;
    }
    __syncthreads();

    unsigned lane = t & 63;
    int w = t >> 6;
    unsigned q  = lane >> 4;   // which edge of the quad
    unsigned hl = lane & 15;   // half2 index in row

    const unsigned int* pp = pairbuf + (size_t)b * BKT_CAP;
    int s0 = (size * w) >> 2;
    int s1 = (size * (w + 1)) >> 2;
    int k = s0;
    for (; k + 8 <= s1; k += 8) {   // 8 edges: 2 pk loads + 2 gathers + 4 ds_add
        unsigned pk0 = pp[k + q];
        unsigned pk1 = pp[k + 4 + q];
        float2 f0 = __half22float2(g2[((pk0 >> 7) << 4) + hl]);
        float2 f1 = __half22float2(g2[((pk1 >> 7) << 4) + hl]);
        unsigned cA = pk0 & 127u, cB = pk1 & 127u;
        atomicAdd(&sacc[cA][2 * hl], f0.x); atomicAdd(&sacc[cA][2 * hl + 1], f0.y);
        atomicAdd(&sacc[cB][2 * hl], f1.x); atomicAdd(&sacc[cB][2 * hl + 1], f1.y);
    }
    for (; k + 4 <= s1; k += 4) {
        unsigned pk = pp[k + q];
        float2 f = __half22float2(g2[((pk >> 7) << 4) + hl]);
        unsigned c = pk & 127u;
        atomicAdd(&sacc[c][2 * hl], f.x); atomicAdd(&sacc[c][2 * hl + 1], f.y);
    }
    int rem = s1 - k;               // 0..3
    if ((int)q < rem) {
        unsigned pk = pp[k + q];
        float2 f = __half22float2(g2[((pk >> 7) << 4) + hl]);
        unsigned c = pk & 127u;
        atomicAdd(&sacc[c][2 * hl], f.x); atomicAdd(&sacc[c][2 * hl + 1], f.y);
    }
    __syncthreads();

    // out = di*(acc+self)+b2, coalesced float2 writes
    for (int idx = t; idx < nb * 16; idx += 256) {
        int d = idx >> 4; int h = idx & 15;
        float2 self = __half22float2(g2[((unsigned)(c0 + d) << 4) + h]);
        float di = dinv[c0 + d];
        float2 bb = *reinterpret_cast<const float2*>(&b2[2 * h]);
        float2 a = *reinterpret_cast<float2*>(&sacc[d][2 * h]);
        out[((unsigned)(c0 + d) << 4) + h] =
            make_float2(fmaf(di, a.x + self.x, bb.x),
                        fmaf(di, a.y + self.y, bb.y));
    }
}

extern "C" void kernel_launch(void* const* d_in, const int* in_sizes, int n_in,
                              void* d_out, int out_size, void* d_ws, size_t ws_size,
                              hipStream_t stream) {
    const float* x  = (const float*)d_in[0];
    const int*   ei = (const int*)d_in[1];   // [2, E]
    const float* W1 = (const float*)d_in[2];
    const float* b1 = (const float*)d_in[3];
    const float* W2 = (const float*)d_in[4];
    const float* b2 = (const float*)d_in[5];
    float2* out = (float2*)d_out;

    const int* row = ei;            // source
    const int* col = ei + NEDGES;   // target

    char* ws = (char*)d_ws;
    size_t off = 0;
    auto alloc = [&](size_t bytes) {
        void* p = ws + off;
        off = (off + bytes + 511) & ~(size_t)511;
        return p;
    };
    int*          gcur    = (int*)         alloc((size_t)NBUK * 4);
    float*        dinv    = (float*)       alloc((size_t)NNODES * 4);
    unsigned int* pairbuf = (unsigned int*)alloc((size_t)NBUK * BKT_CAP * 4);  // lives whole launch
    __half*       g1      = (__half*)      alloc((size_t)NNODES * HID * 2);
    __half*       g2      = (__half*)      alloc((size_t)NNODES * OUTD * 2);

    hipMemsetAsync(gcur, 0, (size_t)NBUK * 4, stream);
    k_pass1<<<P1_BLOCKS, 256, 0, stream>>>(row, col, gcur, pairbuf);
    k_deg<<<NBUK, 256, 0, stream>>>(pairbuf, gcur, dinv);

    {
        int nblk = (NNODES + TILE - 1) / TILE;  // 1563
        k_gemm1<<<nblk, 256, 0, stream>>>(x, W1, dinv, g1);
    }
    k_agg1<<<NBUK, 256, 0, stream>>>((const __half2*)g1, pairbuf, gcur, dinv, b1, W2, g2);
    k_agg2<<<NBUK, 256, 0, stream>>>((const __half2*)g2, pairbuf, gcur, dinv, b2, out);
}

// Round 12
// 287.581 us; speedup vs baseline: 4.2018x; 4.2018x over previous
//
#include <hip/hip_runtime.h>
#include <hip/hip_fp16.h>

// GCN: N=100000 nodes, E=1600000 edges, dims 128 -> 64 -> 32.
// CSR-by-destination via bucketed counting sort (r10 structure, reverted from
// the failed LDS-atomic r11). g1/g2 fp16. Gathers: 4 edges per load instr in
// agg1 (16-lane groups, 8B/lane), 8 edges per load in agg2 (8-lane groups).
// 16-edge unroll -> 4-8 independent loads in flight per wave. fp32 accum.

#define NNODES 100000
#define NEDGES 1600000
#define IN_DIM 128
#define HID 64
#define OUTD 32

#define BKT_NODES 128
#define NBUK 782                        // ceil(100000/128)
#define BKT_CAP 3584                    // slots/bucket; mean load 2048
#define P1_BLOCKS 256
#define P1_CHUNK (NEDGES / P1_BLOCKS)   // 6250 exactly

// ---- CSR build ----

__global__ __launch_bounds__(256) void k_pass1(const int* __restrict__ row,
                                               const int* __restrict__ col,
                                               int* __restrict__ gcur,
                                               unsigned int* __restrict__ pairbuf) {
    __shared__ int lcnt[NBUK];
    __shared__ int lbase[NBUK];
    int t = threadIdx.x;
    int e0 = blockIdx.x * P1_CHUNK;
    int e1 = e0 + P1_CHUNK;
    for (int j = t; j < NBUK; j += 256) lcnt[j] = 0;
    __syncthreads();
    for (int e = e0 + t; e < e1; e += 256)
        atomicAdd(&lcnt[col[e] >> 7], 1);
    __syncthreads();
    for (int j = t; j < NBUK; j += 256) {
        int n = lcnt[j];
        lbase[j] = (n > 0) ? atomicAdd(&gcur[j], n) : 0;
    }
    __syncthreads();
    for (int j = t; j < NBUK; j += 256) lcnt[j] = 0;
    __syncthreads();
    for (int e = e0 + t; e < e1; e += 256) {
        int c = col[e];
        unsigned int pk = ((unsigned int)row[e] << 7) | (unsigned int)(c & 127);
        int b = c >> 7;
        int pos = lbase[b] + atomicAdd(&lcnt[b], 1);
        if (pos < BKT_CAP) pairbuf[(size_t)b * BKT_CAP + pos] = pk;
    }
}

__global__ __launch_bounds__(1024) void k_bktscan(const int* __restrict__ gcur,
                                                  int* __restrict__ bktbase,
                                                  int* __restrict__ ptr) {
    __shared__ int s[1024];
    int t = threadIdx.x;
    int v = (t < NBUK) ? gcur[t] : 0;
    s[t] = v;
    __syncthreads();
    for (int off = 1; off < 1024; off <<= 1) {
        int u = (t >= off) ? s[t - off] : 0;
        __syncthreads();
        s[t] += u;
        __syncthreads();
    }
    if (t < NBUK) bktbase[t] = s[t] - v;  // exclusive
    if (t == 0) { bktbase[NBUK] = NEDGES; ptr[NNODES] = NEDGES; }
}

__global__ __launch_bounds__(256) void k_pass2(const unsigned int* __restrict__ pairbuf,
                                               const int* __restrict__ gcur,
                                               const int* __restrict__ bktbase,
                                               int* __restrict__ ptr,
                                               float* __restrict__ dinv,
                                               int* __restrict__ adj) {
    __shared__ int ncnt[BKT_NODES];
    __shared__ int nsc[BKT_NODES];
    __shared__ int ncur[BKT_NODES];
    __shared__ int seg[BKT_CAP];
    int b = blockIdx.x;
    int t = threadIdx.x;
    int c0 = b * BKT_NODES;
    int nb = NNODES - c0; if (nb > BKT_NODES) nb = BKT_NODES;
    int size = gcur[b]; if (size > BKT_CAP) size = BKT_CAP;
    int base = bktbase[b];
    const unsigned int* pp = pairbuf + (size_t)b * BKT_CAP;

    if (t < BKT_NODES) ncnt[t] = 0;
    __syncthreads();
    for (int k = t; k < size; k += 256)
        atomicAdd(&ncnt[pp[k] & 127u], 1);
    __syncthreads();
    int myv = (t < BKT_NODES) ? ncnt[t] : 0;
    if (t < BKT_NODES) nsc[t] = myv;
    __syncthreads();
    for (int off = 1; off < BKT_NODES; off <<= 1) {
        int u = 0;
        if (t < BKT_NODES && t >= off) u = nsc[t - off];
        __syncthreads();
        if (t < BKT_NODES) nsc[t] += u;
        __syncthreads();
    }
    if (t < BKT_NODES) {
        int excl = nsc[t] - myv;
        ncur[t] = excl;
        if (t < nb) {
            ptr[c0 + t] = base + excl;
            dinv[c0 + t] = rsqrtf((float)myv + 1.0f);  // +1 self-loop
        }
    }
    __syncthreads();
    for (int k = t; k < size; k += 256) {
        unsigned int pk = pp[k];
        int pos = atomicAdd(&ncur[pk & 127u], 1);
        seg[pos] = (int)(pk >> 7);  // LDS scatter (cheap), global stays coalesced
    }
    __syncthreads();
    for (int k = t; k < size; k += 256) adj[base + k] = seg[k];
}

// ---- layer kernels ----

// g1 = fp16(dinv * (x @ W1)); 64-node x-tile staged in LDS via coalesced float4.
#define TILE 64
#define NT 16
__global__ __launch_bounds__(256) void k_gemm1(const float* __restrict__ x,
                                               const float* __restrict__ W1,
                                               const float* __restrict__ dinv,
                                               __half* __restrict__ g1) {
    __shared__ float shx[TILE][IN_DIM];  // 32 KB
    int t = threadIdx.x;
    int nbase = blockIdx.x * TILE;

    const float4* xg = reinterpret_cast<const float4*>(x + (size_t)nbase * IN_DIM);
    float4* shx4 = reinterpret_cast<float4*>(&shx[0][0]);
    int lim = (NNODES - nbase) * (IN_DIM / 4);
    if (lim > TILE * (IN_DIM / 4)) lim = TILE * (IN_DIM / 4);
#pragma unroll
    for (int it = 0; it < 8; ++it) {
        int idx = t + it * 256;
        if (idx < lim) shx4[idx] = xg[idx];
    }
    __syncthreads();

    int w = t >> 6;
    int lane = t & 63;
    int n0 = w * NT;

    float acc[NT];
#pragma unroll
    for (int n = 0; n < NT; ++n) acc[n] = 0.0f;

    for (int kc = 0; kc < IN_DIM / 4; ++kc) {
        float w0 = W1[(kc * 4 + 0) * HID + lane];  // coalesced 256B, L1-hot
        float w1 = W1[(kc * 4 + 1) * HID + lane];
        float w2 = W1[(kc * 4 + 2) * HID + lane];
        float w3 = W1[(kc * 4 + 3) * HID + lane];
#pragma unroll
        for (int n = 0; n < NT; ++n) {
            float4 xv = *reinterpret_cast<const float4*>(&shx[n0 + n][kc * 4]);
            acc[n] = fmaf(xv.x, w0, acc[n]);
            acc[n] = fmaf(xv.y, w1, acc[n]);
            acc[n] = fmaf(xv.z, w2, acc[n]);
            acc[n] = fmaf(xv.w, w3, acc[n]);
        }
    }
#pragma unroll
    for (int n = 0; n < NT; ++n) {
        int node = nbase + n0 + n;
        if (node < NNODES)
            g1[(unsigned)node * HID + lane] = __float2half(dinv[node] * acc[n]);
    }
}

// fused layer1-agg + layer2-gemm. One wave per dest node.
// Gather: 16-lane groups, lane loads uint2 (4 fp16 feats) -> 4 edges per load
// instr; 16-edge unroll -> 4 adj + 4 gather loads in flight. fp32 accum;
// shfl_xor(16,32) combine. Then h1 in LDS, matvec h1@W2.
__global__ __launch_bounds__(256) void k_agg1g2(const uint2* __restrict__ g1q,
                                                const int* __restrict__ ptr,
                                                const int* __restrict__ adj,
                                                const float* __restrict__ dinv,
                                                const float* __restrict__ b1,
                                                const float* __restrict__ W2,
                                                __half* __restrict__ g2) {
    __shared__ float sh[4][HID];
    int t = blockIdx.x * blockDim.x + threadIdx.x;
    int i = t >> 6;
    if (i >= NNODES) return;
    unsigned lane = threadIdx.x & 63;
    int w = threadIdx.x >> 6;
    unsigned q  = lane >> 4;   // which edge of the quad
    unsigned hl = lane & 15;   // uint2 chunk: feats [4hl, 4hl+4)

    float4 acc = make_float4(0.f, 0.f, 0.f, 0.f);
    auto addrow = [&](unsigned n) {
        uint2 v = g1q[(n << 4) + hl];
        float2 fa = __half22float2(*reinterpret_cast<const __half2*>(&v.x));
        float2 fb = __half22float2(*reinterpret_cast<const __half2*>(&v.y));
        acc.x += fa.x; acc.y += fa.y; acc.z += fb.x; acc.w += fb.y;
    };

    if (q == 0) addrow((unsigned)i);  // self loop, counted once
    int p0 = ptr[i], p1 = ptr[i + 1];
    int p = p0;
    for (; p + 16 <= p1; p += 16) {   // 16 edges: 4 adj + 4 gathers in flight
        int n0 = adj[p + q];
        int n1 = adj[p + 4 + q];
        int n2 = adj[p + 8 + q];
        int n3 = adj[p + 12 + q];
        addrow((unsigned)n0);
        addrow((unsigned)n1);
        addrow((unsigned)n2);
        addrow((unsigned)n3);
    }
    for (; p + 4 <= p1; p += 4) {
        int n = adj[p + q];
        addrow((unsigned)n);
    }
    int rem = p1 - p;                  // 0..3
    if ((int)q < rem) {
        int n = adj[p + q];
        addrow((unsigned)n);
    }
    // combine quarters
    acc.x += __shfl_xor(acc.x, 16); acc.y += __shfl_xor(acc.y, 16);
    acc.z += __shfl_xor(acc.z, 16); acc.w += __shfl_xor(acc.w, 16);
    acc.x += __shfl_xor(acc.x, 32); acc.y += __shfl_xor(acc.y, 32);
    acc.z += __shfl_xor(acc.z, 32); acc.w += __shfl_xor(acc.w, 32);

    float di = dinv[i];
    if (q == 0) {
        float4 bb = reinterpret_cast<const float4*>(b1)[hl];
        float4 h;
        h.x = fmaxf(fmaf(di, acc.x, bb.x), 0.f);
        h.y = fmaxf(fmaf(di, acc.y, bb.y), 0.f);
        h.z = fmaxf(fmaf(di, acc.z, bb.z), 0.f);
        h.w = fmaxf(fmaf(di, acc.w, bb.w), 0.f);
        *reinterpret_cast<float4*>(&sh[w][4 * hl]) = h;
    }
    // same wave wrote sh -> wave-synchronous, compiler inserts lgkmcnt wait

    unsigned j2 = lane & 31;
    unsigned half = lane >> 5;
    float mv = 0.0f;
#pragma unroll
    for (int j = 0; j < 32; ++j) {
        unsigned jj = half * 32 + j;
        mv = fmaf(sh[w][jj], W2[jj * OUTD + j2], mv);
    }
    mv += __shfl_xor(mv, 32);
    if (half == 0) g2[((unsigned)i << 5) + j2] = __float2half(di * mv);
}

// out = dinv * (self + sum_nbr) g2 + b2. One wave per node.
// 8-lane groups, lane loads uint2 (4 feats) -> 8 edges per load instr;
// 16-edge unroll -> 2 adj + 2 gathers. shfl_xor(8,16,32) combine.
__global__ __launch_bounds__(256) void k_agg2(const uint2* __restrict__ g2q,
                                              const int* __restrict__ ptr,
                                              const int* __restrict__ adj,
                                              const float* __restrict__ dinv,
                                              const float* __restrict__ b2,
                                              float4* __restrict__ out4) {
    int t = blockIdx.x * blockDim.x + threadIdx.x;
    int i = t >> 6;
    if (i >= NNODES) return;
    unsigned lane = threadIdx.x & 63;
    unsigned q  = lane >> 3;   // which edge of the oct
    unsigned hl = lane & 7;    // uint2 chunk: feats [4hl, 4hl+4)

    float4 acc = make_float4(0.f, 0.f, 0.f, 0.f);
    auto addrow = [&](unsigned n) {
        uint2 v = g2q[(n << 3) + hl];
        float2 fa = __half22float2(*reinterpret_cast<const __half2*>(&v.x));
        float2 fb = __half22float2(*reinterpret_cast<const __half2*>(&v.y));
        acc.x += fa.x; acc.y += fa.y; acc.z += fb.x; acc.w += fb.y;
    };

    if (q == 0) addrow((unsigned)i);  // self loop once
    int p0 = ptr[i], p1 = ptr[i + 1];
    int p = p0;
    for (; p + 16 <= p1; p += 16) {   // 16 edges: 2 adj + 2 gathers
        int n0 = adj[p + q];
        int n1 = adj[p + 8 + q];
        addrow((unsigned)n0);
        addrow((unsigned)n1);
    }
    for (; p + 8 <= p1; p += 8) {
        int n = adj[p + q];
        addrow((unsigned)n);
    }
    int rem = p1 - p;                  // 0..7
    if ((int)q < rem) {
        int n = adj[p + q];
        addrow((unsigned)n);
    }
    acc.x += __shfl_xor(acc.x, 8);  acc.y += __shfl_xor(acc.y, 8);
    acc.z += __shfl_xor(acc.z, 8);  acc.w += __shfl_xor(acc.w, 8);
    acc.x += __shfl_xor(acc.x, 16); acc.y += __shfl_xor(acc.y, 16);
    acc.z += __shfl_xor(acc.z, 16); acc.w += __shfl_xor(acc.w, 16);
    acc.x += __shfl_xor(acc.x, 32); acc.y += __shfl_xor(acc.y, 32);
    acc.z += __shfl_xor(acc.z, 32); acc.w += __shfl_xor(acc.w, 32);

    if (q == 0) {
        float di = dinv[i];
        float4 bb = reinterpret_cast<const float4*>(b2)[hl];
        out4[((unsigned)i << 3) + hl] =
            make_float4(fmaf(di, acc.x, bb.x), fmaf(di, acc.y, bb.y),
                        fmaf(di, acc.z, bb.z), fmaf(di, acc.w, bb.w));
    }
}

extern "C" void kernel_launch(void* const* d_in, const int* in_sizes, int n_in,
                              void* d_out, int out_size, void* d_ws, size_t ws_size,
                              hipStream_t stream) {
    const float* x  = (const float*)d_in[0];
    const int*   ei = (const int*)d_in[1];   // [2, E]
    const float* W1 = (const float*)d_in[2];
    const float* b1 = (const float*)d_in[3];
    const float* W2 = (const float*)d_in[4];
    const float* b2 = (const float*)d_in[5];
    float4* out = (float4*)d_out;

    const int* row = ei;            // source
    const int* col = ei + NEDGES;   // target

    char* ws = (char*)d_ws;
    size_t off = 0;
    auto alloc = [&](size_t bytes) {
        void* p = ws + off;
        off = (off + bytes + 511) & ~(size_t)511;
        return p;
    };
    int*    gcur    = (int*)   alloc((size_t)NBUK * 4);
    int*    bktbase = (int*)   alloc((size_t)(NBUK + 1) * 4);
    int*    ptr     = (int*)   alloc((size_t)(NNODES + 1) * 4);
    float*  dinv    = (float*) alloc((size_t)NNODES * 4);
    int*    adj     = (int*)   alloc((size_t)NEDGES * 4);
    __half* g2      = (__half*)alloc((size_t)NNODES * OUTD * 2);
    // pairbuf (11.2MB) and g1 (12.8MB) share one region: pairbuf dead after k_pass2.
    size_t big = (size_t)NBUK * BKT_CAP * 4;
    size_t g1b = (size_t)NNODES * HID * 2;
    unsigned int* pairbuf = (unsigned int*)alloc(big > g1b ? big : g1b);
    __half* g1 = (__half*)pairbuf;

    const int B = 256;
    hipMemsetAsync(gcur, 0, (size_t)NBUK * 4, stream);
    k_pass1<<<P1_BLOCKS, 256, 0, stream>>>(row, col, gcur, pairbuf);
    k_bktscan<<<1, 1024, 0, stream>>>(gcur, bktbase, ptr);
    k_pass2<<<NBUK, 256, 0, stream>>>(pairbuf, gcur, bktbase, ptr, dinv, adj);

    {
        int nblk = (NNODES + TILE - 1) / TILE;  // 1563
        k_gemm1<<<nblk, 256, 0, stream>>>(x, W1, dinv, g1);
    }
    {
        long long tot = (long long)NNODES * 64;
        k_agg1g2<<<(int)((tot + B - 1) / B), B, 0, stream>>>(
            (const uint2*)g1, ptr, adj, dinv, b1, W2, g2);
    }
    {
        long long tot = (long long)NNODES * 64;
        k_agg2<<<(int)((tot + B - 1) / B), B, 0, stream>>>(
            (const uint2*)g2, ptr, adj, dinv, b2, out);
    }
}

// Round 14
// 286.852 us; speedup vs baseline: 4.2125x; 1.0025x over previous
//
#include <hip/hip_runtime.h>
#include <hip/hip_fp16.h>

// GCN: N=100000 nodes, E=1600000 edges, dims 128 -> 64 -> 32.
// CSR-by-destination via bucketed counting sort. g1/g2 fp16, fp32 accum.
// r13: bktscan folded into pass2 (per-block prefix over 782 bucket counts);
// agg1g2 split into two half-grid dispatches (reveals hidden #2 kernel in
// profile top-5; agg1g2 itself is at its structural plateau ~72us combined).

#define NNODES 100000
#define NEDGES 1600000
#define IN_DIM 128
#define HID 64
#define OUTD 32

#define BKT_NODES 128
#define NBUK 782                        // ceil(100000/128)
#define BKT_CAP 3584                    // slots/bucket; mean load 2048
#define P1_BLOCKS 256
#define P1_CHUNK (NEDGES / P1_BLOCKS)   // 6250 exactly

// ---- CSR build ----

__global__ __launch_bounds__(256) void k_pass1(const int* __restrict__ row,
                                               const int* __restrict__ col,
                                               int* __restrict__ gcur,
                                               unsigned int* __restrict__ pairbuf) {
    __shared__ int lcnt[NBUK];
    __shared__ int lbase[NBUK];
    int t = threadIdx.x;
    int e0 = blockIdx.x * P1_CHUNK;
    int e1 = e0 + P1_CHUNK;
    for (int j = t; j < NBUK; j += 256) lcnt[j] = 0;
    __syncthreads();
    for (int e = e0 + t; e < e1; e += 256)
        atomicAdd(&lcnt[col[e] >> 7], 1);
    __syncthreads();
    for (int j = t; j < NBUK; j += 256) {
        int n = lcnt[j];
        lbase[j] = (n > 0) ? atomicAdd(&gcur[j], n) : 0;
    }
    __syncthreads();
    for (int j = t; j < NBUK; j += 256) lcnt[j] = 0;
    __syncthreads();
    for (int e = e0 + t; e < e1; e += 256) {
        int c = col[e];
        unsigned int pk = ((unsigned int)row[e] << 7) | (unsigned int)(c & 127);
        int b = c >> 7;
        int pos = lbase[b] + atomicAdd(&lcnt[b], 1);
        if (pos < BKT_CAP) pairbuf[(size_t)b * BKT_CAP + pos] = pk;
    }
}

// pass2: per-bucket CSR build. Bucket base computed in-block (prefix over gcur)
// -- replaces the former single-block bktscan kernel.
__global__ __launch_bounds__(256) void k_pass2(const unsigned int* __restrict__ pairbuf,
                                               const int* __restrict__ gcur,
                                               int* __restrict__ ptr,
                                               float* __restrict__ dinv,
                                               int* __restrict__ adj) {
    __shared__ int ncnt[BKT_NODES];
    __shared__ int nsc[BKT_NODES];
    __shared__ int ncur[BKT_NODES];
    __shared__ int red[256];
    __shared__ int seg[BKT_CAP];
    int b = blockIdx.x;
    int t = threadIdx.x;

    // base = sum_{j<b} gcur[j]  (782 values, L2-hot)
    int part = 0;
    for (int j = t; j < b; j += 256) part += gcur[j];
    red[t] = part;
    __syncthreads();
    for (int o = 128; o > 0; o >>= 1) {
        if (t < o) red[t] += red[t + o];
        __syncthreads();
    }
    int base = red[0];

    int c0 = b * BKT_NODES;
    int nb = NNODES - c0; if (nb > BKT_NODES) nb = BKT_NODES;
    int size = gcur[b]; if (size > BKT_CAP) size = BKT_CAP;
    const unsigned int* pp = pairbuf + (size_t)b * BKT_CAP;

    if (t < BKT_NODES) ncnt[t] = 0;
    __syncthreads();
    for (int k = t; k < size; k += 256)
        atomicAdd(&ncnt[pp[k] & 127u], 1);
    __syncthreads();
    int myv = (t < BKT_NODES) ? ncnt[t] : 0;
    if (t < BKT_NODES) nsc[t] = myv;
    __syncthreads();
    for (int off = 1; off < BKT_NODES; off <<= 1) {
        int u = 0;
        if (t < BKT_NODES && t >= off) u = nsc[t - off];
        __syncthreads();
        if (t < BKT_NODES) nsc[t] += u;
        __syncthreads();
    }
    if (t < BKT_NODES) {
        int excl = nsc[t] - myv;
        ncur[t] = excl;
        if (t < nb) {
            ptr[c0 + t] = base + excl;
            dinv[c0 + t] = rsqrtf((float)myv + 1.0f);  // +1 self-loop
        }
    }
    if (b == NBUK - 1 && t == 0) ptr[NNODES] = NEDGES;
    __syncthreads();
    for (int k = t; k < size; k += 256) {
        unsigned int pk = pp[k];
        int pos = atomicAdd(&ncur[pk & 127u], 1);
        seg[pos] = (int)(pk >> 7);  // LDS scatter (cheap), global stays coalesced
    }
    __syncthreads();
    for (int k = t; k < size; k += 256) adj[base + k] = seg[k];
}

// ---- layer kernels ----

// g1 = fp16(dinv * (x @ W1)); 64-node x-tile staged in LDS via coalesced float4.
#define TILE 64
#define NT 16
__global__ __launch_bounds__(256) void k_gemm1(const float* __restrict__ x,
                                               const float* __restrict__ W1,
                                               const float* __restrict__ dinv,
                                               __half* __restrict__ g1) {
    __shared__ float shx[TILE][IN_DIM];  // 32 KB
    int t = threadIdx.x;
    int nbase = blockIdx.x * TILE;

    const float4* xg = reinterpret_cast<const float4*>(x + (size_t)nbase * IN_DIM);
    float4* shx4 = reinterpret_cast<float4*>(&shx[0][0]);
    int lim = (NNODES - nbase) * (IN_DIM / 4);
    if (lim > TILE * (IN_DIM / 4)) lim = TILE * (IN_DIM / 4);
#pragma unroll
    for (int it = 0; it < 8; ++it) {
        int idx = t + it * 256;
        if (idx < lim) shx4[idx] = xg[idx];
    }
    __syncthreads();

    int w = t >> 6;
    int lane = t & 63;
    int n0 = w * NT;

    float acc[NT];
#pragma unroll
    for (int n = 0; n < NT; ++n) acc[n] = 0.0f;

    for (int kc = 0; kc < IN_DIM / 4; ++kc) {
        float w0 = W1[(kc * 4 + 0) * HID + lane];  // coalesced 256B, L1-hot
        float w1 = W1[(kc * 4 + 1) * HID + lane];
        float w2 = W1[(kc * 4 + 2) * HID + lane];
        float w3 = W1[(kc * 4 + 3) * HID + lane];
#pragma unroll
        for (int n = 0; n < NT; ++n) {
            float4 xv = *reinterpret_cast<const float4*>(&shx[n0 + n][kc * 4]);
            acc[n] = fmaf(xv.x, w0, acc[n]);
            acc[n] = fmaf(xv.y, w1, acc[n]);
            acc[n] = fmaf(xv.z, w2, acc[n]);
            acc[n] = fmaf(xv.w, w3, acc[n]);
        }
    }
#pragma unroll
    for (int n = 0; n < NT; ++n) {
        int node = nbase + n0 + n;
        if (node < NNODES)
            g1[(unsigned)node * HID + lane] = __float2half(dinv[node] * acc[n]);
    }
}

// fused layer1-agg + layer2-gemm. One wave per dest node (node = ibase + wid).
// 16-lane groups, lane loads uint2 (4 fp16 feats) -> 4 edges per load instr.
__global__ __launch_bounds__(256) void k_agg1g2(const uint2* __restrict__ g1q,
                                                const int* __restrict__ ptr,
                                                const int* __restrict__ adj,
                                                const float* __restrict__ dinv,
                                                const float* __restrict__ b1,
                                                const float* __restrict__ W2,
                                                __half* __restrict__ g2,
                                                int ibase) {
    __shared__ float sh[4][HID];
    int t = blockIdx.x * blockDim.x + threadIdx.x;
    int i = ibase + (t >> 6);
    if (i >= NNODES) return;
    unsigned lane = threadIdx.x & 63;
    int w = threadIdx.x >> 6;
    unsigned q  = lane >> 4;   // which edge of the quad
    unsigned hl = lane & 15;   // uint2 chunk: feats [4hl, 4hl+4)

    float4 acc = make_float4(0.f, 0.f, 0.f, 0.f);
    auto addrow = [&](unsigned n) {
        uint2 v = g1q[(n << 4) + hl];
        float2 fa = __half22float2(*reinterpret_cast<const __half2*>(&v.x));
        float2 fb = __half22float2(*reinterpret_cast<const __half2*>(&v.y));
        acc.x += fa.x; acc.y += fa.y; acc.z += fb.x; acc.w += fb.y;
    };

    if (q == 0) addrow((unsigned)i);  // self loop, counted once
    int p0 = ptr[i], p1 = ptr[i + 1];
    int p = p0;
    for (; p + 16 <= p1; p += 16) {   // 16 edges: 4 adj + 4 gathers in flight
        int n0 = adj[p + q];
        int n1 = adj[p + 4 + q];
        int n2 = adj[p + 8 + q];
        int n3 = adj[p + 12 + q];
        addrow((unsigned)n0);
        addrow((unsigned)n1);
        addrow((unsigned)n2);
        addrow((unsigned)n3);
    }
    for (; p + 4 <= p1; p += 4) {
        int n = adj[p + q];
        addrow((unsigned)n);
    }
    int rem = p1 - p;                  // 0..3
    if ((int)q < rem) {
        int n = adj[p + q];
        addrow((unsigned)n);
    }
    acc.x += __shfl_xor(acc.x, 16); acc.y += __shfl_xor(acc.y, 16);
    acc.z += __shfl_xor(acc.z, 16); acc.w += __shfl_xor(acc.w, 16);
    acc.x += __shfl_xor(acc.x, 32); acc.y += __shfl_xor(acc.y, 32);
    acc.z += __shfl_xor(acc.z, 32); acc.w += __shfl_xor(acc.w, 32);

    float di = dinv[i];
    if (q == 0) {
        float4 bb = reinterpret_cast<const float4*>(b1)[hl];
        float4 h;
        h.x = fmaxf(fmaf(di, acc.x, bb.x), 0.f);
        h.y = fmaxf(fmaf(di, acc.y, bb.y), 0.f);
        h.z = fmaxf(fmaf(di, acc.z, bb.z), 0.f);
        h.w = fmaxf(fmaf(di, acc.w, bb.w), 0.f);
        *reinterpret_cast<float4*>(&sh[w][4 * hl]) = h;
    }
    // same wave wrote sh -> wave-synchronous, compiler inserts lgkmcnt wait

    unsigned j2 = lane & 31;
    unsigned half = lane >> 5;
    float mv = 0.0f;
#pragma unroll
    for (int j = 0; j < 32; ++j) {
        unsigned jj = half * 32 + j;
        mv = fmaf(sh[w][jj], W2[jj * OUTD + j2], mv);
    }
    mv += __shfl_xor(mv, 32);
    if (half == 0) g2[((unsigned)i << 5) + j2] = __float2half(di * mv);
}

// out = dinv * (self + sum_nbr) g2 + b2. One wave per node.
// 8-lane groups, lane loads uint2 (4 feats) -> 8 edges per load instr.
__global__ __launch_bounds__(256) void k_agg2(const uint2* __restrict__ g2q,
                                              const int* __restrict__ ptr,
                                              const int* __restrict__ adj,
                                              const float* __restrict__ dinv,
                                              const float* __restrict__ b2,
                                              float4* __restrict__ out4) {
    int t = blockIdx.x * blockDim.x + threadIdx.x;
    int i = t >> 6;
    if (i >= NNODES) return;
    unsigned lane = threadIdx.x & 63;
    unsigned q  = lane >> 3;   // which edge of the oct
    unsigned hl = lane & 7;    // uint2 chunk: feats [4hl, 4hl+4)

    float4 acc = make_float4(0.f, 0.f, 0.f, 0.f);
    auto addrow = [&](unsigned n) {
        uint2 v = g2q[(n << 3) + hl];
        float2 fa = __half22float2(*reinterpret_cast<const __half2*>(&v.x));
        float2 fb = __half22float2(*reinterpret_cast<const __half2*>(&v.y));
        acc.x += fa.x; acc.y += fa.y; acc.z += fb.x; acc.w += fb.y;
    };

    if (q == 0) addrow((unsigned)i);  // self loop once
    int p0 = ptr[i], p1 = ptr[i + 1];
    int p = p0;
    for (; p + 16 <= p1; p += 16) {   // 16 edges: 2 adj + 2 gathers
        int n0 = adj[p + q];
        int n1 = adj[p + 8 + q];
        addrow((unsigned)n0);
        addrow((unsigned)n1);
    }
    for (; p + 8 <= p1; p += 8) {
        int n = adj[p + q];
        addrow((unsigned)n);
    }
    int rem = p1 - p;                  // 0..7
    if ((int)q < rem) {
        int n = adj[p + q];
        addrow((unsigned)n);
    }
    acc.x += __shfl_xor(acc.x, 8);  acc.y += __shfl_xor(acc.y, 8);
    acc.z += __shfl_xor(acc.z, 8);  acc.w += __shfl_xor(acc.w, 8);
    acc.x += __shfl_xor(acc.x, 16); acc.y += __shfl_xor(acc.y, 16);
    acc.z += __shfl_xor(acc.z, 16); acc.w += __shfl_xor(acc.w, 16);
    acc.x += __shfl_xor(acc.x, 32); acc.y += __shfl_xor(acc.y, 32);
    acc.z += __shfl_xor(acc.z, 32); acc.w += __shfl_xor(acc.w, 32);

    if (q == 0) {
        float di = dinv[i];
        float4 bb = reinterpret_cast<const float4*>(b2)[hl];
        out4[((unsigned)i << 3) + hl] =
            make_float4(fmaf(di, acc.x, bb.x), fmaf(di, acc.y, bb.y),
                        fmaf(di, acc.z, bb.z), fmaf(di, acc.w, bb.w));
    }
}

extern "C" void kernel_launch(void* const* d_in, const int* in_sizes, int n_in,
                              void* d_out, int out_size, void* d_ws, size_t ws_size,
                              hipStream_t stream) {
    const float* x  = (const float*)d_in[0];
    const int*   ei = (const int*)d_in[1];   // [2, E]
    const float* W1 = (const float*)d_in[2];
    const float* b1 = (const float*)d_in[3];
    const float* W2 = (const float*)d_in[4];
    const float* b2 = (const float*)d_in[5];
    float4* out = (float4*)d_out;

    const int* row = ei;            // source
    const int* col = ei + NEDGES;   // target

    char* ws = (char*)d_ws;
    size_t off = 0;
    auto alloc = [&](size_t bytes) {
        void* p = ws + off;
        off = (off + bytes + 511) & ~(size_t)511;
        return p;
    };
    int*    gcur = (int*)   alloc((size_t)NBUK * 4);
    int*    ptr  = (int*)   alloc((size_t)(NNODES + 1) * 4);
    float*  dinv = (float*) alloc((size_t)NNODES * 4);
    int*    adj  = (int*)   alloc((size_t)NEDGES * 4);
    __half* g2   = (__half*)alloc((size_t)NNODES * OUTD * 2);
    // pairbuf (11.2MB) and g1 (12.8MB) share one region: pairbuf dead after k_pass2.
    size_t big = (size_t)NBUK * BKT_CAP * 4;
    size_t g1b = (size_t)NNODES * HID * 2;
    unsigned int* pairbuf = (unsigned int*)alloc(big > g1b ? big : g1b);
    __half* g1 = (__half*)pairbuf;

    const int B = 256;
    hipMemsetAsync(gcur, 0, (size_t)NBUK * 4, stream);
    k_pass1<<<P1_BLOCKS, 256, 0, stream>>>(row, col, gcur, pairbuf);
    k_pass2<<<NBUK, 256, 0, stream>>>(pairbuf, gcur, ptr, dinv, adj);

    {
        int nblk = (NNODES + TILE - 1) / TILE;  // 1563
        k_gemm1<<<nblk, 256, 0, stream>>>(x, W1, dinv, g1);
    }
    {
        // split into two half-grids: diagnostic (expose #2 kernel in top-5)
        const int H0 = 50048;                       // multiple of 4 nodes/block
        int nblk0 = H0 / 4;                         // 12512
        int nblk1 = (NNODES - H0 + 3) / 4;          // 12488
        k_agg1g2<<<nblk0, B, 0, stream>>>(
            (const uint2*)g1, ptr, adj, dinv, b1, W2, g2, 0);
        k_agg1g2<<<nblk1, B, 0, stream>>>(
            (const uint2*)g1, ptr, adj, dinv, b1, W2, g2, H0);
    }
    {
        long long tot = (long long)NNODES * 64;
        k_agg2<<<(int)((tot + B - 1) / B), B, 0, stream>>>(
            (const uint2*)g2, ptr, adj, dinv, b2, out);
    }
}

// Round 15
// 256.991 us; speedup vs baseline: 4.7020x; 1.1162x over previous
//
#include <hip/hip_runtime.h>
#include <hip/hip_fp16.h>

// GCN: N=100000 nodes, E=1600000 edges, dims 128 -> 64 -> 32.
// CSR-by-destination via bucketed counting sort. g1/g2 fp16, fp32 accum.
// r15: gemm1 via MFMA f32_16x16x32_f16 (fp16 in, fp32 acc). W1 pre-packed to
// per-fragment fp16 layout by k_cvtW; A-fragments from global x with in-flight
// cvt; B entirely in VGPRs; no LDS. k-slot mapping identical for A and B
// (permutation-invariant over k), C/D layout per m89: col=lane&15,
// row=(lane>>4)*4+reg.

#define NNODES 100000
#define NEDGES 1600000
#define IN_DIM 128
#define HID 64
#define OUTD 32

#define BKT_NODES 128
#define NBUK 782                        // ceil(100000/128)
#define BKT_CAP 3584                    // slots/bucket; mean load 2048
#define P1_BLOCKS 256
#define P1_CHUNK (NEDGES / P1_BLOCKS)   // 6250 exactly

typedef _Float16 f16x8 __attribute__((ext_vector_type(8)));
typedef float f32x4 __attribute__((ext_vector_type(4)));

// ---- CSR build ----

__global__ __launch_bounds__(256) void k_pass1(const int* __restrict__ row,
                                               const int* __restrict__ col,
                                               int* __restrict__ gcur,
                                               unsigned int* __restrict__ pairbuf) {
    __shared__ int lcnt[NBUK];
    __shared__ int lbase[NBUK];
    int t = threadIdx.x;
    int e0 = blockIdx.x * P1_CHUNK;
    int e1 = e0 + P1_CHUNK;
    for (int j = t; j < NBUK; j += 256) lcnt[j] = 0;
    __syncthreads();
    for (int e = e0 + t; e < e1; e += 256)
        atomicAdd(&lcnt[col[e] >> 7], 1);
    __syncthreads();
    for (int j = t; j < NBUK; j += 256) {
        int n = lcnt[j];
        lbase[j] = (n > 0) ? atomicAdd(&gcur[j], n) : 0;
    }
    __syncthreads();
    for (int j = t; j < NBUK; j += 256) lcnt[j] = 0;
    __syncthreads();
    for (int e = e0 + t; e < e1; e += 256) {
        int c = col[e];
        unsigned int pk = ((unsigned int)row[e] << 7) | (unsigned int)(c & 127);
        int b = c >> 7;
        int pos = lbase[b] + atomicAdd(&lcnt[b], 1);
        if (pos < BKT_CAP) pairbuf[(size_t)b * BKT_CAP + pos] = pk;
    }
}

// pass2: per-bucket CSR build; bucket base via in-block prefix over gcur.
__global__ __launch_bounds__(256) void k_pass2(const unsigned int* __restrict__ pairbuf,
                                               const int* __restrict__ gcur,
                                               int* __restrict__ ptr,
                                               float* __restrict__ dinv,
                                               int* __restrict__ adj) {
    __shared__ int ncnt[BKT_NODES];
    __shared__ int nsc[BKT_NODES];
    __shared__ int ncur[BKT_NODES];
    __shared__ int red[256];
    __shared__ int seg[BKT_CAP];
    int b = blockIdx.x;
    int t = threadIdx.x;

    int part = 0;
    for (int j = t; j < b; j += 256) part += gcur[j];
    red[t] = part;
    __syncthreads();
    for (int o = 128; o > 0; o >>= 1) {
        if (t < o) red[t] += red[t + o];
        __syncthreads();
    }
    int base = red[0];

    int c0 = b * BKT_NODES;
    int nb = NNODES - c0; if (nb > BKT_NODES) nb = BKT_NODES;
    int size = gcur[b]; if (size > BKT_CAP) size = BKT_CAP;
    const unsigned int* pp = pairbuf + (size_t)b * BKT_CAP;

    if (t < BKT_NODES) ncnt[t] = 0;
    __syncthreads();
    for (int k = t; k < size; k += 256)
        atomicAdd(&ncnt[pp[k] & 127u], 1);
    __syncthreads();
    int myv = (t < BKT_NODES) ? ncnt[t] : 0;
    if (t < BKT_NODES) nsc[t] = myv;
    __syncthreads();
    for (int off = 1; off < BKT_NODES; off <<= 1) {
        int u = 0;
        if (t < BKT_NODES && t >= off) u = nsc[t - off];
        __syncthreads();
        if (t < BKT_NODES) nsc[t] += u;
        __syncthreads();
    }
    if (t < BKT_NODES) {
        int excl = nsc[t] - myv;
        ncur[t] = excl;
        if (t < nb) {
            ptr[c0 + t] = base + excl;
            dinv[c0 + t] = rsqrtf((float)myv + 1.0f);  // +1 self-loop
        }
    }
    if (b == NBUK - 1 && t == 0) ptr[NNODES] = NEDGES;
    __syncthreads();
    for (int k = t; k < size; k += 256) {
        unsigned int pk = pp[k];
        int pos = atomicAdd(&ncur[pk & 127u], 1);
        seg[pos] = (int)(pk >> 7);
    }
    __syncthreads();
    for (int k = t; k < size; k += 256) adj[base + k] = seg[k];
}

// ---- layer kernels ----

// Pre-pack W1 (128x64 fp32) into fp16 MFMA B-fragments.
// frag slot = kk*4+nt; lane l, elem j holds W1[kk*32+(l>>4)*8+j][nt*16+(l&15)].
__global__ __launch_bounds__(256) void k_cvtW(const float* __restrict__ W1,
                                              _Float16* __restrict__ W1h) {
    int t = threadIdx.x;
#pragma unroll
    for (int it = 0; it < 4; ++it) {
        int fl = t + it * 256;       // fragment-lane id 0..1023
        int slot = fl >> 6;
        int l = fl & 63;
        int kk = slot >> 2, nt = slot & 3;
        int kbase = kk * 32 + ((l >> 4) << 3);
        int n = nt * 16 + (l & 15);
        _Float16* dst = W1h + (size_t)fl * 8;
#pragma unroll
        for (int j = 0; j < 8; ++j)
            dst[j] = (_Float16)W1[(kbase + j) * HID + n];
    }
}

// g1 = fp16(dinv * (x @ W1)) via MFMA. Block = 4 waves; wave w owns 16 nodes.
// No LDS. B (entire W1) in 64 VGPRs; A from global x with in-flight f32->f16.
__global__ __launch_bounds__(256) void k_gemm1(const float* __restrict__ x,
                                               const f16x8* __restrict__ W1h,
                                               const float* __restrict__ dinv,
                                               __half* __restrict__ g1) {
    int w = threadIdx.x >> 6;
    int l = threadIdx.x & 63;
    int nbase = blockIdx.x * 64 + w * 16;
    if (nbase >= NNODES) return;   // 100000 = 6250 full waves, per-wave guard ok

    f16x8 bf[16];
#pragma unroll
    for (int s = 0; s < 16; ++s) bf[s] = W1h[s * 64 + l];  // coalesced 16B/lane

    f32x4 acc[4] = {};
    const float* xrow = x + (size_t)(nbase + (l & 15)) * IN_DIM + ((l >> 4) << 3);
#pragma unroll
    for (int kk = 0; kk < 4; ++kk) {
        float4 a0 = *reinterpret_cast<const float4*>(xrow + kk * 32);
        float4 a1 = *reinterpret_cast<const float4*>(xrow + kk * 32 + 4);
        f16x8 af;
        af[0] = (_Float16)a0.x; af[1] = (_Float16)a0.y;
        af[2] = (_Float16)a0.z; af[3] = (_Float16)a0.w;
        af[4] = (_Float16)a1.x; af[5] = (_Float16)a1.y;
        af[6] = (_Float16)a1.z; af[7] = (_Float16)a1.w;
#pragma unroll
        for (int nt = 0; nt < 4; ++nt)
            acc[nt] = __builtin_amdgcn_mfma_f32_16x16x32_f16(af, bf[kk * 4 + nt],
                                                             acc[nt], 0, 0, 0);
    }
    // C/D: col = l&15, row = (l>>4)*4 + r  [m89-verified]
    int rbase = nbase + ((l >> 4) << 2);
    float dv[4];
#pragma unroll
    for (int r = 0; r < 4; ++r) dv[r] = dinv[rbase + r];
#pragma unroll
    for (int nt = 0; nt < 4; ++nt) {
        int feat = nt * 16 + (l & 15);
#pragma unroll
        for (int r = 0; r < 4; ++r)
            g1[(size_t)(rbase + r) * HID + feat] = __float2half(dv[r] * acc[nt][r]);
    }
}

// fused layer1-agg + layer2-gemm. One wave per dest node.
// 16-lane groups, lane loads uint2 (4 fp16 feats) -> 4 edges per load instr.
__global__ __launch_bounds__(256) void k_agg1g2(const uint2* __restrict__ g1q,
                                                const int* __restrict__ ptr,
                                                const int* __restrict__ adj,
                                                const float* __restrict__ dinv,
                                                const float* __restrict__ b1,
                                                const float* __restrict__ W2,
                                                __half* __restrict__ g2) {
    __shared__ float sh[4][HID];
    int t = blockIdx.x * blockDim.x + threadIdx.x;
    int i = t >> 6;
    if (i >= NNODES) return;
    unsigned lane = threadIdx.x & 63;
    int w = threadIdx.x >> 6;
    unsigned q  = lane >> 4;
    unsigned hl = lane & 15;

    float4 acc = make_float4(0.f, 0.f, 0.f, 0.f);
    auto addrow = [&](unsigned n) {
        uint2 v = g1q[(n << 4) + hl];
        float2 fa = __half22float2(*reinterpret_cast<const __half2*>(&v.x));
        float2 fb = __half22float2(*reinterpret_cast<const __half2*>(&v.y));
        acc.x += fa.x; acc.y += fa.y; acc.z += fb.x; acc.w += fb.y;
    };

    if (q == 0) addrow((unsigned)i);  // self loop, counted once
    int p0 = ptr[i], p1 = ptr[i + 1];
    int p = p0;
    for (; p + 16 <= p1; p += 16) {
        int n0 = adj[p + q];
        int n1 = adj[p + 4 + q];
        int n2 = adj[p + 8 + q];
        int n3 = adj[p + 12 + q];
        addrow((unsigned)n0);
        addrow((unsigned)n1);
        addrow((unsigned)n2);
        addrow((unsigned)n3);
    }
    for (; p + 4 <= p1; p += 4) {
        int n = adj[p + q];
        addrow((unsigned)n);
    }
    int rem = p1 - p;
    if ((int)q < rem) {
        int n = adj[p + q];
        addrow((unsigned)n);
    }
    acc.x += __shfl_xor(acc.x, 16); acc.y += __shfl_xor(acc.y, 16);
    acc.z += __shfl_xor(acc.z, 16); acc.w += __shfl_xor(acc.w, 16);
    acc.x += __shfl_xor(acc.x, 32); acc.y += __shfl_xor(acc.y, 32);
    acc.z += __shfl_xor(acc.z, 32); acc.w += __shfl_xor(acc.w, 32);

    float di = dinv[i];
    if (q == 0) {
        float4 bb = reinterpret_cast<const float4*>(b1)[hl];
        float4 h;
        h.x = fmaxf(fmaf(di, acc.x, bb.x), 0.f);
        h.y = fmaxf(fmaf(di, acc.y, bb.y), 0.f);
        h.z = fmaxf(fmaf(di, acc.z, bb.z), 0.f);
        h.w = fmaxf(fmaf(di, acc.w, bb.w), 0.f);
        *reinterpret_cast<float4*>(&sh[w][4 * hl]) = h;
    }
    // same wave wrote sh -> wave-synchronous

    unsigned j2 = lane & 31;
    unsigned half = lane >> 5;
    float mv = 0.0f;
#pragma unroll
    for (int j = 0; j < 32; ++j) {
        unsigned jj = half * 32 + j;
        mv = fmaf(sh[w][jj], W2[jj * OUTD + j2], mv);
    }
    mv += __shfl_xor(mv, 32);
    if (half == 0) g2[((unsigned)i << 5) + j2] = __float2half(di * mv);
}

// out = dinv * (self + sum_nbr) g2 + b2. One wave per node.
// 8-lane groups, lane loads uint2 (4 feats) -> 8 edges per load instr.
__global__ __launch_bounds__(256) void k_agg2(const uint2* __restrict__ g2q,
                                              const int* __restrict__ ptr,
                                              const int* __restrict__ adj,
                                              const float* __restrict__ dinv,
                                              const float* __restrict__ b2,
                                              float4* __restrict__ out4) {
    int t = blockIdx.x * blockDim.x + threadIdx.x;
    int i = t >> 6;
    if (i >= NNODES) return;
    unsigned lane = threadIdx.x & 63;
    unsigned q  = lane >> 3;
    unsigned hl = lane & 7;

    float4 acc = make_float4(0.f, 0.f, 0.f, 0.f);
    auto addrow = [&](unsigned n) {
        uint2 v = g2q[(n << 3) + hl];
        float2 fa = __half22float2(*reinterpret_cast<const __half2*>(&v.x));
        float2 fb = __half22float2(*reinterpret_cast<const __half2*>(&v.y));
        acc.x += fa.x; acc.y += fa.y; acc.z += fb.x; acc.w += fb.y;
    };

    if (q == 0) addrow((unsigned)i);  // self loop once
    int p0 = ptr[i], p1 = ptr[i + 1];
    int p = p0;
    for (; p + 16 <= p1; p += 16) {
        int n0 = adj[p + q];
        int n1 = adj[p + 8 + q];
        addrow((unsigned)n0);
        addrow((unsigned)n1);
    }
    for (; p + 8 <= p1; p += 8) {
        int n = adj[p + q];
        addrow((unsigned)n);
    }
    int rem = p1 - p;
    if ((int)q < rem) {
        int n = adj[p + q];
        addrow((unsigned)n);
    }
    acc.x += __shfl_xor(acc.x, 8);  acc.y += __shfl_xor(acc.y, 8);
    acc.z += __shfl_xor(acc.z, 8);  acc.w += __shfl_xor(acc.w, 8);
    acc.x += __shfl_xor(acc.x, 16); acc.y += __shfl_xor(acc.y, 16);
    acc.z += __shfl_xor(acc.z, 16); acc.w += __shfl_xor(acc.w, 16);
    acc.x += __shfl_xor(acc.x, 32); acc.y += __shfl_xor(acc.y, 32);
    acc.z += __shfl_xor(acc.z, 32); acc.w += __shfl_xor(acc.w, 32);

    if (q == 0) {
        float di = dinv[i];
        float4 bb = reinterpret_cast<const float4*>(b2)[hl];
        out4[((unsigned)i << 3) + hl] =
            make_float4(fmaf(di, acc.x, bb.x), fmaf(di, acc.y, bb.y),
                        fmaf(di, acc.z, bb.z), fmaf(di, acc.w, bb.w));
    }
}

extern "C" void kernel_launch(void* const* d_in, const int* in_sizes, int n_in,
                              void* d_out, int out_size, void* d_ws, size_t ws_size,
                              hipStream_t stream) {
    const float* x  = (const float*)d_in[0];
    const int*   ei = (const int*)d_in[1];   // [2, E]
    const float* W1 = (const float*)d_in[2];
    const float* b1 = (const float*)d_in[3];
    const float* W2 = (const float*)d_in[4];
    const float* b2 = (const float*)d_in[5];
    float4* out = (float4*)d_out;

    const int* row = ei;            // source
    const int* col = ei + NEDGES;   // target

    char* ws = (char*)d_ws;
    size_t off = 0;
    auto alloc = [&](size_t bytes) {
        void* p = ws + off;
        off = (off + bytes + 511) & ~(size_t)511;
        return p;
    };
    int*       gcur = (int*)      alloc((size_t)NBUK * 4);
    int*       ptr  = (int*)      alloc((size_t)(NNODES + 1) * 4);
    float*     dinv = (float*)    alloc((size_t)NNODES * 4);
    int*       adj  = (int*)      alloc((size_t)NEDGES * 4);
    __half*    g2   = (__half*)   alloc((size_t)NNODES * OUTD * 2);
    _Float16*  W1h  = (_Float16*) alloc((size_t)IN_DIM * HID * 2);  // 16 KB
    // pairbuf (11.2MB) and g1 (12.8MB) share one region: pairbuf dead after k_pass2.
    size_t big = (size_t)NBUK * BKT_CAP * 4;
    size_t g1b = (size_t)NNODES * HID * 2;
    unsigned int* pairbuf = (unsigned int*)alloc(big > g1b ? big : g1b);
    __half* g1 = (__half*)pairbuf;

    const int B = 256;
    hipMemsetAsync(gcur, 0, (size_t)NBUK * 4, stream);
    k_cvtW<<<1, 256, 0, stream>>>(W1, W1h);
    k_pass1<<<P1_BLOCKS, 256, 0, stream>>>(row, col, gcur, pairbuf);
    k_pass2<<<NBUK, 256, 0, stream>>>(pairbuf, gcur, ptr, dinv, adj);

    {
        int nblk = (NNODES + 63) / 64;  // 1563
        k_gemm1<<<nblk, 256, 0, stream>>>(x, (const f16x8*)W1h, dinv, g1);
    }
    {
        long long tot = (long long)NNODES * 64;
        k_agg1g2<<<(int)((tot + B - 1) / B), B, 0, stream>>>(
            (const uint2*)g1, ptr, adj, dinv, b1, W2, g2);
    }
    {
        long long tot = (long long)NNODES * 64;
        k_agg2<<<(int)((tot + B - 1) / B), B, 0, stream>>>(
            (const uint2*)g2, ptr, adj, dinv, b2, out);
    }
}